// Round 1
// baseline (1783.793 us; speedup 1.0000x reference)
//
#include <hip/hip_runtime.h>
#include <math.h>

// Problem constants (B=4, S=512, H=2048, E=16, K=4)
#define M_TOK 2048   // B*S tokens
#define H_    2048
#define H2_   1024
#define E_    16
#define CAP_  768
#define ALPHA_ 0.7f

// ---------------------------------------------------------------------------
// Generic tiled fp32 GEMM: C[M,N] = act(A[M,K] @ W[K,N] + bias[N])
// 64x64 tile, BK=16, 256 threads, 4x4 microtile per thread.
// A row-major [M,K], W row-major [K,N]. M,N,K multiples of 64/64/16.
// ---------------------------------------------------------------------------
__global__ __launch_bounds__(256) void gemm_bias_kernel(
    const float* __restrict__ A, const float* __restrict__ W,
    const float* __restrict__ bias, float* __restrict__ C,
    int M, int N, int K, int relu)
{
    __shared__ float As[16][64];   // [k][m] (transposed at load)
    __shared__ float Bs[16][64];   // [k][n]

    const int tid = threadIdx.x;
    const int bm = blockIdx.y * 64;
    const int bn = blockIdx.x * 64;
    const int tx = tid & 15;        // col group 0..15
    const int ty = tid >> 4;        // row group 0..15

    // load mapping: A tile 64 rows x 16 k, one float4 per thread
    const int arow = tid >> 2;           // 0..63
    const int ak4  = (tid & 3) << 2;     // 0,4,8,12
    // W tile 16 k x 64 n, one float4 per thread
    const int bk   = tid >> 4;           // 0..15
    const int bn4  = (tid & 15) << 2;    // 0..60

    float acc[4][4];
#pragma unroll
    for (int i = 0; i < 4; ++i)
#pragma unroll
        for (int j = 0; j < 4; ++j) acc[i][j] = 0.f;

    const float* Aload = A + (size_t)(bm + arow) * K + ak4;
    const float* Wload = W + (size_t)bk * N + bn + bn4;

    for (int k0 = 0; k0 < K; k0 += 16) {
        float4 a4 = *(const float4*)(Aload + k0);
        float4 b4 = *(const float4*)(Wload + (size_t)k0 * N);
        As[ak4 + 0][arow] = a4.x;
        As[ak4 + 1][arow] = a4.y;
        As[ak4 + 2][arow] = a4.z;
        As[ak4 + 3][arow] = a4.w;
        *(float4*)&Bs[bk][bn4] = b4;
        __syncthreads();

#pragma unroll
        for (int k = 0; k < 16; ++k) {
            float4 av = *(const float4*)&As[k][ty << 2];
            float4 bv = *(const float4*)&Bs[k][tx << 2];
            float a[4] = {av.x, av.y, av.z, av.w};
            float b[4] = {bv.x, bv.y, bv.z, bv.w};
#pragma unroll
            for (int i = 0; i < 4; ++i)
#pragma unroll
                for (int j = 0; j < 4; ++j) acc[i][j] = fmaf(a[i], b[j], acc[i][j]);
        }
        __syncthreads();
    }

    const float4 bb = *(const float4*)&bias[bn + (tx << 2)];
    const float bvec[4] = {bb.x, bb.y, bb.z, bb.w};
#pragma unroll
    for (int i = 0; i < 4; ++i) {
        float4 o;
        o.x = acc[i][0] + bvec[0];
        o.y = acc[i][1] + bvec[1];
        o.z = acc[i][2] + bvec[2];
        o.w = acc[i][3] + bvec[3];
        if (relu) {
            o.x = fmaxf(o.x, 0.f); o.y = fmaxf(o.y, 0.f);
            o.z = fmaxf(o.z, 0.f); o.w = fmaxf(o.w, 0.f);
        }
        *(float4*)&C[(size_t)(bm + (ty << 2) + i) * N + bn + (tx << 2)] = o;
    }
}

// ---------------------------------------------------------------------------
// Skinny GEMM for logits: C[M,16] = A[M,K] @ W[K,16] + bias[16]
// block 256 = 16 rows x 16 experts; grid M/16.
// ---------------------------------------------------------------------------
__global__ __launch_bounds__(256) void gemm_n16_kernel(
    const float* __restrict__ A, const float* __restrict__ W,
    const float* __restrict__ bias, float* __restrict__ C, int K)
{
    __shared__ float As[16][64];
    const int tid = threadIdx.x;
    const int e = tid & 15;        // expert
    const int r = tid >> 4;        // row-in-block
    const int row0 = blockIdx.x * 16;

    const int lr  = tid >> 4;            // load row 0..15
    const int lk4 = (tid & 15) << 2;     // load k offset

    float acc = 0.f;
    for (int k0 = 0; k0 < K; k0 += 64) {
        *(float4*)&As[lr][lk4] =
            *(const float4*)&A[(size_t)(row0 + lr) * K + k0 + lk4];
        __syncthreads();
#pragma unroll 16
        for (int k = 0; k < 64; ++k)
            acc = fmaf(As[r][k], W[(size_t)(k0 + k) * E_ + e], acc);
        __syncthreads();
    }
    C[(size_t)(row0 + r) * E_ + e] = acc + bias[e];
}

// ---------------------------------------------------------------------------
// Router finalize: per-token softmaxes, mix, top-4, scatter slot-0, probs,
// per-expert sum accumulation for aux loss.
// ---------------------------------------------------------------------------
__device__ __forceinline__ void softmax16_acc(const float* __restrict__ lg,
                                              float w, float* __restrict__ p)
{
    float mx = lg[0];
#pragma unroll
    for (int e = 1; e < 16; ++e) mx = fmaxf(mx, lg[e]);
    float ex[16];
    float s = 0.f;
#pragma unroll
    for (int e = 0; e < 16; ++e) { ex[e] = expf(lg[e] - mx); s += ex[e]; }
    const float wi = w / s;
#pragma unroll
    for (int e = 0; e < 16; ++e) p[e] = fmaf(ex[e], wi, p[e]);
}

__global__ __launch_bounds__(256) void router_kernel(
    const float* __restrict__ GL,   // [M,16]
    const float* __restrict__ SL,   // [4,M,16]
    float* __restrict__ out, float* __restrict__ accum)
{
    const int t = blockIdx.x * 256 + threadIdx.x;
    if (t >= M_TOK) return;

    float p[16];
#pragma unroll
    for (int e = 0; e < 16; ++e) p[e] = 0.f;

    softmax16_acc(GL + (size_t)t * E_, ALPHA_, p);
    // (1-ALPHA) * (sum of 4 modality softmaxes) / NUM_AVAILABLE(=2)
#pragma unroll
    for (int m = 0; m < 4; ++m)
        softmax16_acc(SL + ((size_t)m * M_TOK + t) * E_, (1.f - ALPHA_) * 0.5f, p);

    const size_t NTOT = (size_t)M_TOK * E_ * CAP_;
    float* probs_out = out + 2 * NTOT + (size_t)t * E_;
#pragma unroll
    for (int e = 0; e < 16; ++e) {
        probs_out[e] = p[e];
        atomicAdd(&accum[e], p[e]);
    }

    // top-4, ties -> lowest index (matches jax.lax.top_k)
    float tmp[16];
#pragma unroll
    for (int e = 0; e < 16; ++e) tmp[e] = p[e];
    int   bi[4];
    float bv[4];
    float s4 = 0.f;
#pragma unroll
    for (int kk = 0; kk < 4; ++kk) {
        float best = -1.f; int besti = 0;
#pragma unroll
        for (int e = 0; e < 16; ++e) {
            if (tmp[e] > best) { best = tmp[e]; besti = e; }
        }
        bi[kk] = besti; bv[kk] = best; s4 += best;
        tmp[besti] = -1.f;
    }
    const float inv = 1.f / s4;
#pragma unroll
    for (int kk = 0; kk < 4; ++kk) {
        const size_t base = ((size_t)t * E_ + bi[kk]) * CAP_;
        out[base] = 1.0f;                    // dispatch_tensor slot 0
        out[NTOT + base] = bv[kk] * inv;     // combine_tensor  slot 0
    }
}

__global__ void aux_kernel(const float* __restrict__ accum,
                           float* __restrict__ out, unsigned long long pos)
{
    if (threadIdx.x == 0 && blockIdx.x == 0) {
        float s = 0.f;
#pragma unroll
        for (int e = 0; e < 16; ++e) {
            float m = accum[e] * (1.0f / (float)M_TOK);
            s += m * logf(m * (float)E_ + 1e-9f);
        }
        out[pos] = s;
    }
}

// ---------------------------------------------------------------------------
extern "C" void kernel_launch(void* const* d_in, const int* in_sizes, int n_in,
                              void* d_out, int out_size, void* d_ws, size_t ws_size,
                              hipStream_t stream)
{
    const float* hidden = (const float*)d_in[0];
    const float* mimg   = (const float*)d_in[1];
    const float* mgen   = (const float*)d_in[2];
    const float* Wg1 = (const float*)d_in[3];
    const float* bg1 = (const float*)d_in[4];
    const float* Wg2 = (const float*)d_in[5];
    const float* bg2 = (const float*)d_in[6];
    const float* Wm1 = (const float*)d_in[7];
    const float* bm1 = (const float*)d_in[8];
    const float* Wm2 = (const float*)d_in[9];
    const float* bm2 = (const float*)d_in[10];
    const float* Ws1 = (const float*)d_in[11];  // [4,H,H2]
    const float* bs1 = (const float*)d_in[12];  // [4,H2]
    const float* Ws2 = (const float*)d_in[13];  // [4,H2,E]
    const float* bs2 = (const float*)d_in[14];  // [4,E]

    float* out = (float*)d_out;
    float* ws = (float*)d_ws;

    // workspace layout (floats)
    float* accum = ws;                                   // 16
    float* T1    = ws + 16;                              // [M,H]
    float* MISS  = T1   + (size_t)M_TOK * H_;            // [M,H]
    float* G1    = MISS + (size_t)M_TOK * H_;            // [M,H]
    float* S1    = G1   + (size_t)M_TOK * H_;            // [4][M,H2]
    float* GL    = S1   + (size_t)4 * M_TOK * H2_;       // [M,E]
    float* SL    = GL   + (size_t)M_TOK * E_;            // [4][M,E]

    // zero entire output (dispatch/combine are mostly structural zeros)
    hipMemsetAsync(d_out, 0, (size_t)out_size * sizeof(float), stream);
    hipMemsetAsync(accum, 0, 16 * sizeof(float), stream);

    const dim3 blk(256);
    const dim3 gHH(H_ / 64, M_TOK / 64);    // N=2048 tiles
    const dim3 gH2(H2_ / 64, M_TOK / 64);   // N=1024 tiles

    // missing-modality encoder
    gemm_bias_kernel<<<gHH, blk, 0, stream>>>(hidden, Wm1, bm1, T1,   M_TOK, H_, H_, 1);
    gemm_bias_kernel<<<gHH, blk, 0, stream>>>(T1,     Wm2, bm2, MISS, M_TOK, H_, H_, 0);
    // generalized router
    gemm_bias_kernel<<<gHH, blk, 0, stream>>>(hidden, Wg1, bg1, G1,   M_TOK, H_, H_, 1);
    gemm_n16_kernel<<<M_TOK / 16, blk, 0, stream>>>(G1, Wg2, bg2, GL, H_);
    // specialized routers: [image, genomic, missing, missing]
    const float* data[4] = {mimg, mgen, MISS, MISS};
    for (int m = 0; m < 4; ++m) {
        gemm_bias_kernel<<<gH2, blk, 0, stream>>>(
            data[m], Ws1 + (size_t)m * H_ * H2_, bs1 + (size_t)m * H2_,
            S1 + (size_t)m * M_TOK * H2_, M_TOK, H2_, H_, 1);
        gemm_n16_kernel<<<M_TOK / 16, blk, 0, stream>>>(
            S1 + (size_t)m * M_TOK * H2_, Ws2 + (size_t)m * H2_ * E_,
            bs2 + (size_t)m * E_, SL + (size_t)m * M_TOK * E_, H2_);
    }
    // finalize
    router_kernel<<<M_TOK / 256, blk, 0, stream>>>(GL, SL, out, accum);
    aux_kernel<<<1, 64, 0, stream>>>(accum, out, (unsigned long long)out_size - 1);
}